// Round 10
// baseline (112.865 us; speedup 1.0000x reference)
//
#include <hip/hip_runtime.h>
#include <math.h>

// DiffKS: time-varying 7-tap sparse IIR.
//   y[n] = x[n] + sum_{i=0..6} block_i[n] * y[n - zc[n] - i],  zc in [37,97].
// Max lag 103 -> 103-sample state. Linear => segmented superposition:
//   phase1: per (batch,segment) run 103 unit-state + 1 particular IIRs
//           (wave = sample, lanes = runs -> conflict-free LDS rows). ~22us.
//   fused compose+scan (NEW): 256 blocks; block (b,s) REDUNDANTLY composes
//           its own incoming state with a single-wave, barrier-free pipeline
//           (no __syncthreads in the chain -> no vmcnt(0) drains, which were
//           phase2's structural ~800cyc/step cost), then scans its segment.
//           Waves 1-3 stage coeffs concurrently.

#define B_    16
#define N_    16384
#define S_    16
#define NSEG  1024
#define NITER 28      // ceil(1024/37)
#define RUNS  104     // 103 unit columns + 1 particular
#define CHUNK 37      // min dependency distance (zc >= 37)

#define TG_FLOATS (B_ * S_ * RUNS * RUNS)

// ---- shared coeff math (proven round-2..9 formulas) ----
__device__ __forceinline__ void diffks_coeffs(float f0v, float lbg, float lbp,
                                              int n, float4& lo, float4& hi) {
  float g  = 0.99f * lbg;
  float p  = lbp;
  float b0 = g * (1.0f - p);
  float a1 = g * p;
  float f0c = f0v - a1 / (b0 + a1 + 1e-7f);
  int   zc  = (int)floorf(f0c) - 2;
  float alpha = f0c - (float)zc;
  float u0 = alpha;
  float u1 = alpha - 1.0f;
  float u2 = alpha - 2.0f;
  float u3 = alpha - 3.0f;
  float u4 = alpha - 4.0f;
  float u5 = alpha - 5.0f;
  float w0 = u1 * u2 * u3 * u4 * u5 * (-1.0f / 120.0f);
  float w1 = u0 * u2 * u3 * u4 * u5 * ( 1.0f /  24.0f);
  float w2 = u0 * u1 * u3 * u4 * u5 * (-1.0f /  12.0f);
  float w3 = u0 * u1 * u2 * u4 * u5 * ( 1.0f /  12.0f);
  float w4 = u0 * u1 * u2 * u3 * u5 * (-1.0f /  24.0f);
  float w5 = u0 * u1 * u2 * u3 * u4 * ( 1.0f / 120.0f);
  lo.x = b0 * w0;                   // block0
  lo.y = fmaf(b0, w1, a1 * w0);     // block1
  lo.z = fmaf(b0, w2, a1 * w1);     // block2
  lo.w = fmaf(b0, w3, a1 * w2);     // block3
  hi.x = fmaf(b0, w4, a1 * w3);     // block4
  hi.y = fmaf(b0, w5, a1 * w4);     // block5
  hi.z = a1 * w5;                   // block6
  hi.w = __int_as_float((n - 6 - zc) & 255);   // ring base row (pos mod 256)
}

// =================== Phase 1: T matrices (runs-major) — unchanged ===================
__global__ __launch_bounds__(1024) void diffks_phase1(
    const float* __restrict__ f0, const float* __restrict__ lb,
    const float* __restrict__ x, float* __restrict__ Tg) {
  const int bs = blockIdx.x;
  const int b  = bs >> 4, s = bs & 15;
  const int n0 = s << 10;
  const int tid = threadIdx.x;

  __shared__ __align__(16) float hist[256 * RUNS];   // 104 KB
  __shared__ float4 sLo[NSEG], sHi[NSEG];            // 32 KB
  __shared__ float  sX[NSEG];                        // 4 KB

  {
    const size_t gi = (size_t)b * N_ + n0 + tid;
    float4 lo, hi;
    diffks_coeffs(f0[gi], lb[2 * gi], lb[2 * gi + 1], tid, lo, hi);
    sLo[tid] = lo; sHi[tid] = hi; sX[tid] = x[gi];
  }
  for (int i = tid; i < 64 * RUNS; i += 1024)
    ((float4*)hist)[i] = float4{0.0f, 0.0f, 0.0f, 0.0f};
  __syncthreads();
  if (tid < 103) hist[(255 - tid) * RUNS + tid] = 1.0f;  // e_r at pos -1-r
  __syncthreads();

  const int w    = tid >> 6;      // wave 0..15
  const int lane = tid & 63;
  const int cl   = 2 * lane;      // run columns cl, cl+1
  const bool act = (lane < 52);
  const bool px  = (lane == 51);  // .y of lane 51 is run 103 (particular)

  for (int t = 0; t < 32; ++t) {
#pragma unroll
    for (int u = 0; u < 2; ++u) {
      const int p = 32 * t + 2 * w + u;       // 32 consecutive samples/round
      const float4 lo = sLo[p];               // wave-uniform -> broadcast
      const float4 hi = sHi[p];
      const float  xv = sX[p];
      if (act) {
        const int base = __float_as_int(hi.w);   // row of oldest tap
        float2 acc;
        acc.x = 0.0f;
        acc.y = px ? xv : 0.0f;
        const float c[7] = {hi.z, hi.y, hi.x, lo.w, lo.z, lo.y, lo.x};
#pragma unroll
        for (int m = 0; m < 7; ++m) {
          const int row = (base + m) & 255;
          const float2 v = *(const float2*)&hist[row * RUNS + cl];
          acc.x = fmaf(c[m], v.x, acc.x);
          acc.y = fmaf(c[m], v.y, acc.y);
        }
        *(float2*)&hist[(p & 255) * RUNS + cl] = acc;
      }
    }
    __syncthreads();   // publish this round's 32 samples to all waves
  }

  // emit RUNS-MAJOR: T[r][j] = run r at position 1023-j (row (255-j)&255)
  float* __restrict__ T = Tg + (size_t)bs * RUNS * RUNS;
  for (int idx = tid; idx < RUNS * RUNS; idx += 1024) {
    const int r = idx / RUNS;
    const int j = idx - r * RUNS;
    T[idx] = (j < 103) ? hist[((255 - j) & 255) * RUNS + r] : 0.0f;
  }
}

// =================== Fused compose + scan ===================
// grid 256 (= b*16+s), block 256 (4 waves).
// Wave 0: compose state over segments 0..s-1, ALONE (no block barriers in the
//   chain). cur in wave-private LDS; T streamed through 4 statically-named
//   register buffers, distance-4 group prefetch -> per-wave in-order vmcnt
//   pipelining with no drains. Then scan the segment (round-9 proven body).
// Waves 1-3: concurrently stage sC/sX (coeffs VALU-recomputed).

// load group (13 rows) of T into BUF; lane l covers run cols cl, cl+1
#define CG_LOAD(BUF, Tbase, rbase)                                           \
  { _Pragma("unroll") for (int kk = 0; kk < 13; ++kk)                        \
      BUF[kk] = *(const float2*)&(Tbase)[((rbase) + kk) * RUNS + cl]; }

// consume group: acc[kk&3] += BUF[kk] * curL[rbase+kk]  (broadcast reads)
#define CG_FMA(BUF, rbase)                                                   \
  { _Pragma("unroll") for (int kk = 0; kk < 13; ++kk) {                      \
      const float cv = curL[(rbase) + kk];                                   \
      acc[kk & 3].x = fmaf(BUF[kk].x, cv, acc[kk & 3].x);                    \
      acc[kk & 3].y = fmaf(BUF[kk].y, cv, acc[kk & 3].y); } }

__global__ __launch_bounds__(256, 1) void diffks_compose_scan(
    const float* __restrict__ Tg, const float* __restrict__ f0,
    const float* __restrict__ lb, const float* __restrict__ x,
    float* __restrict__ y) {
  const int bs = blockIdx.x;
  const int b  = bs >> 4, s = bs & 15;
  const int n0 = s << 10;
  const int tid = threadIdx.x;

  __shared__ __align__(16) float ring[512];   // mirrored mod-256 ring
  __shared__ __align__(16) float4 sC[2 * NSEG];  // interleaved lo/hi (32 KB)
  __shared__ float  sX[NSEG];
  __shared__ float  sY[NSEG];
  __shared__ float  curL[RUNS];               // wave-0-private compose state

  // ring zero + curL init, then one cheap barrier
  ring[tid] = 0.0f; ring[tid + 256] = 0.0f;
  if (tid < 52) {
    float2 iv; iv.x = 0.0f; iv.y = (tid == 51) ? 1.0f : 0.0f;  // cur[103]=1
    *(float2*)&curL[2 * tid] = iv;
  }
  __syncthreads();   // #1

  if (tid < 64) {
    // ---------- wave 0: barrier-free compose ----------
    const int l  = tid;
    const int cl = 2 * l;                     // run cols cl, cl+1 (l<52)
    if (l < 52 && s > 0) {
      const float* __restrict__ Tb = Tg + (size_t)(b * S_) * RUNS * RUNS;
      float2 B0[13], B1[13], B2[13], B3[13];
      float2 acc[4];
      CG_LOAD(B0, Tb, 0)
      CG_LOAD(B1, Tb, 13)
      CG_LOAD(B2, Tb, 26)
      CG_LOAD(B3, Tb, 39)
      for (int k = 0; k < s; ++k) {
        const float* __restrict__ Tk = Tb + (size_t)k * RUNS * RUNS;
        const float* __restrict__ Tn =
            Tb + (size_t)((k + 1 < s) ? k + 1 : k) * RUNS * RUNS;
#pragma unroll
        for (int a = 0; a < 4; ++a) { acc[a].x = 0.0f; acc[a].y = 0.0f; }
        CG_FMA(B0, 0)   CG_LOAD(B0, Tk, 52)
        CG_FMA(B1, 13)  CG_LOAD(B1, Tk, 65)
        CG_FMA(B2, 26)  CG_LOAD(B2, Tk, 78)
        CG_FMA(B3, 39)  CG_LOAD(B3, Tk, 91)
        CG_FMA(B0, 52)  CG_LOAD(B0, Tn, 0)
        CG_FMA(B1, 65)  CG_LOAD(B1, Tn, 13)
        CG_FMA(B2, 78)  CG_LOAD(B2, Tn, 26)
        CG_FMA(B3, 91)  CG_LOAD(B3, Tn, 39)
        float2 nw;
        nw.x = (acc[0].x + acc[1].x) + (acc[2].x + acc[3].x);
        nw.y = (acc[0].y + acc[1].y) + (acc[2].y + acc[3].y);
        if (l == 51) nw.y = 1.0f;             // cur[103] stays 1 (particular)
        *(float2*)&curL[cl] = nw;
        // single wave: in-order DS => next step's broadcasts see this write
        __builtin_amdgcn_wave_barrier();
        asm volatile("" ::: "memory");
      }
    }
    __builtin_amdgcn_wave_barrier();
    asm volatile("" ::: "memory");
    // incoming state k at seg-local pos -1-k -> ring row 255-k (+ mirror).
    {
      const float v = curL[l];                // k = l (0..63)
      ring[255 - l] = v; ring[511 - l] = v;
      if (l < 39) {
        const float v2 = curL[l + 64];        // k = 64..102
        ring[191 - l] = v2; ring[447 - l] = v2;
      }
    }
  } else {
    // ---------- waves 1-3: stage coeffs + x for this segment ----------
    const size_t gb = (size_t)b * N_ + n0;
    for (int i = tid - 64; i < NSEG; i += 192) {
      const size_t gi = gb + i;
      float4 lo, hi;
      diffks_coeffs(f0[gi], lb[2 * gi], lb[2 * gi + 1], n0 + i, lo, hi);
      sC[2 * i] = lo; sC[2 * i + 1] = hi; sX[i] = x[gi];
    }
  }
  __syncthreads();   // #2: staging + states visible

  if (tid < 64) {
    const int lane = tid;
    const bool act = (lane < CHUNK);
    for (int t = 0; t < NITER; ++t) {
      const int p = t * CHUNK + lane;
      if (act && p < NSEG) {
        const float4 lo = sC[2 * p];
        const float4 hi = sC[2 * p + 1];
        const float  xv = sX[p];
        const int base = __float_as_int(hi.w);   // (p-6-zc)&255
        const float r0 = ring[base + 0];
        const float r1 = ring[base + 1];
        const float r2 = ring[base + 2];
        const float r3 = ring[base + 3];
        const float r4 = ring[base + 4];
        const float r5 = ring[base + 5];
        const float r6 = ring[base + 6];
        const float s0 = fmaf(lo.x, r6, xv);
        const float s1 = fmaf(lo.y, r5, lo.z * r4);
        const float s2 = fmaf(lo.w, r3, hi.x * r2);
        const float s3 = fmaf(hi.y, r1, hi.z * r0);
        const float yv = (s0 + s1) + (s2 + s3);
        const int wsl = p & 255;
        ring[wsl]       = yv;
        ring[wsl + 256] = yv;
        sY[p] = yv;
      }
      __builtin_amdgcn_wave_barrier();
      asm volatile("" ::: "memory");
    }
  }
  __syncthreads();   // #3

  float4* __restrict__ yb = (float4*)(y + (size_t)b * N_ + n0);
  yb[tid] = ((const float4*)sY)[tid];
}

// =================== Fallback (proven round-2 path) ===================
__global__ __launch_bounds__(256) void diffks_coeff_fb(
    const float* __restrict__ f0, const float* __restrict__ lb,
    float* __restrict__ cw, int total, int Nmask) {
  int idx = blockIdx.x * blockDim.x + threadIdx.x;
  if (idx >= total) return;
  float4 lo, hi;
  diffks_coeffs(f0[idx], lb[2 * idx], lb[2 * idx + 1], idx & Nmask, lo, hi);
  float4* out4 = (float4*)cw;
  out4[2 * idx]     = lo;
  out4[2 * idx + 1] = hi;
}

__global__ __launch_bounds__(64) void diffks_scan_fb(
    const float* __restrict__ x, const float* __restrict__ cw,
    float* __restrict__ y, int N) {
  const int b    = blockIdx.x;
  const int lane = threadIdx.x;
  __shared__ float ring[512];
#pragma unroll
  for (int i = 0; i < 8; ++i) ring[lane + 64 * i] = 0.0f;
  __builtin_amdgcn_wave_barrier();
  asm volatile("" ::: "memory");
  const float4* __restrict__ c4 = (const float4*)(cw + (size_t)b * N * 8);
  const float*  __restrict__ xb = x + (size_t)b * N;
  float*        __restrict__ yb = y + (size_t)b * N;
  const bool act = (lane < CHUNK);
  const int nIter = (N + CHUNK - 1) / CHUNK;
  for (int t = 0; t < nIter; ++t) {
    const int n = t * CHUNK + lane;
    if (act && n < N) {
      const float4 lo = c4[2 * n];
      const float4 hi = c4[2 * n + 1];
      const float  xv = xb[n];
      const int base = __float_as_int(hi.w);
      const float r0 = ring[base + 0];
      const float r1 = ring[base + 1];
      const float r2 = ring[base + 2];
      const float r3 = ring[base + 3];
      const float r4 = ring[base + 4];
      const float r5 = ring[base + 5];
      const float r6 = ring[base + 6];
      const float s0 = fmaf(lo.x, r6, xv);
      const float s1 = fmaf(lo.y, r5, lo.z * r4);
      const float s2 = fmaf(lo.w, r3, hi.x * r2);
      const float s3 = fmaf(hi.y, r1, hi.z * r0);
      const float yv = (s0 + s1) + (s2 + s3);
      ring[n & 255]         = yv;
      ring[(n & 255) + 256] = yv;
      yb[n] = yv;
    }
    __builtin_amdgcn_wave_barrier();
    asm volatile("" ::: "memory");
  }
}

extern "C" void kernel_launch(void* const* d_in, const int* in_sizes, int n_in,
                              void* d_out, int out_size, void* d_ws, size_t ws_size,
                              hipStream_t stream) {
  const float* f0 = (const float*)d_in[0];
  const float* x  = (const float*)d_in[1];
  const float* lb = (const float*)d_in[2];
  float* out = (float*)d_out;

  const int total = in_sizes[0];
  const size_t need = (size_t)TG_FLOATS * 4;

  if (total == B_ * N_ && ws_size >= need) {
    float* Tg = (float*)d_ws;
    diffks_phase1<<<B_ * S_, 1024, 0, stream>>>(f0, lb, x, Tg);
    diffks_compose_scan<<<B_ * S_, 256, 0, stream>>>(Tg, f0, lb, x, out);
  } else {
    const int N = total / B_;
    float* cw = (float*)d_ws;
    diffks_coeff_fb<<<(total + 255) / 256, 256, 0, stream>>>(f0, lb, cw, total, N - 1);
    diffks_scan_fb<<<B_, 64, 0, stream>>>(x, cw, out, N);
  }
}